// Round 1
// baseline (41.490 us; speedup 1.0000x reference)
//
#include <hip/hip_runtime.h>

// Problem geometry (fixed by reference): rgbd [4,4,512,512] f32, use channels 0..2.
#define HW        262144          // 512*512
#define PER_BATCH 786432          // 3*HW (channels 0..2 are contiguous per batch)
#define NVEC      786432          // total used floats / 4 = 4*3*HW/4
#define KSUB      8               // sub-bins per unit bin
#define NSUB      2048            // 256*KSUB
#define NHIST     6144            // 3*NSUB
#define WIN       64              // window half-width in sub-bins (|v-x| <= 8)
#define P_INV     (1.0f / 1048576.0f)   // 1 / (4*512*512) pixels per channel

// ---------------- Kernel 1: hard sub-bin histogram -------------------------
__global__ __launch_bounds__(1024) void hist_kernel(const float* __restrict__ in,
                                                    unsigned* __restrict__ ghist) {
    __shared__ unsigned lhist[NHIST];
    for (int i = threadIdx.x; i < NHIST; i += blockDim.x) lhist[i] = 0u;
    __syncthreads();

    const int stride = gridDim.x * blockDim.x;
    for (int idx = blockIdx.x * blockDim.x + threadIdx.x; idx < NVEC; idx += stride) {
        const int u = idx * 4;                 // compact float index over 3-channel data
        const int b = u / PER_BATCH;           // batch
        const int r = u - b * PER_BATCH;       // offset within batch's 3-channel block
        const float4 v = *reinterpret_cast<const float4*>(in + (size_t)b * (4 * HW) + r);
        const float vals[4] = {v.x, v.y, v.z, v.w};
#pragma unroll
        for (int j = 0; j < 4; ++j) {
            const int ch = (r + j) >> 18;                  // / HW -> channel 0..2
            const float x = 127.5f * (vals[j] + 1.0f);     // map [-1,1] -> [0,255]
            int q = __float2int_rn(x * (float)KSUB);       // nearest sub-bin
            q = min(max(q, 0), NSUB - 1);
            atomicAdd(&lhist[ch * NSUB + q], 1u);
        }
    }
    __syncthreads();

    for (int i = threadIdx.x; i < NHIST; i += blockDim.x) {
        const unsigned c = lhist[i];
        if (c) atomicAdd(&ghist[i], c);
    }
}

// ---------------- Kernel 2: Gaussian conv over sub-bins + L2 loss ----------
__global__ __launch_bounds__(256) void conv_loss_kernel(const unsigned* __restrict__ ghist,
                                                        float* __restrict__ out) {
    __shared__ float fh[NHIST];
    __shared__ float w[2 * WIN + 1];
    __shared__ float red[256];

    for (int i = threadIdx.x; i < NHIST; i += 256) fh[i] = (float)ghist[i];
    for (int i = threadIdx.x; i < 2 * WIN + 1; i += 256) {
        const float d = (float)(i - WIN) / (float)KSUB;
        w[i] = 0.5f * expf(-0.5f * d * d);
    }
    __syncthreads();

    float acc = 0.0f;
    for (int p = threadIdx.x; p < 768; p += 256) {          // 3 channels * 256 bins
        const int c = p >> 8;
        const int vbin = p & 255;
        const int center = vbin * KSUB;
        const int q0 = max(center - WIN, 0);
        const int q1 = min(center + WIN, NSUB - 1);
        float s = 0.0f;
        for (int q = q0; q <= q1; ++q)
            s += fh[c * NSUB + q] * w[q - center + WIN];
        const float h = s * P_INV;
        const float d = h - (1.0f / 256.0f);
        acc += d * d;
    }

    red[threadIdx.x] = acc;
    __syncthreads();
    for (int off = 128; off > 0; off >>= 1) {
        if (threadIdx.x < off) red[threadIdx.x] += red[threadIdx.x + off];
        __syncthreads();
    }
    if (threadIdx.x == 0) out[0] = red[0];
}

// ---------------------------------------------------------------------------
extern "C" void kernel_launch(void* const* d_in, const int* in_sizes, int n_in,
                              void* d_out, int out_size, void* d_ws, size_t ws_size,
                              hipStream_t stream) {
    const float* in = (const float*)d_in[0];
    float* out = (float*)d_out;
    unsigned* ghist = (unsigned*)d_ws;

    hipMemsetAsync(d_ws, 0, NHIST * sizeof(unsigned), stream);
    hist_kernel<<<256, 1024, 0, stream>>>(in, ghist);
    conv_loss_kernel<<<1, 256, 0, stream>>>(ghist, out);
}

// Round 2
// 40.062 us; speedup vs baseline: 1.0356x; 1.0356x over previous
//
#include <hip/hip_runtime.h>

// Problem geometry (fixed by reference): rgbd [4,4,512,512] f32, use channels 0..2.
#define HW        262144          // 512*512
#define PER_BATCH 786432          // 3*HW (channels 0..2 contiguous per batch)
#define NVEC      786432          // used floats / 4 = 4*3*HW/4
#define KSUB      8               // sub-bins per unit bin
#define NSUB      2048            // 256*KSUB
#define NHIST     6144            // 3*NSUB
#define WIN       64              // window half-width in sub-bins (|v-x| <= 8)
#define P_INV     (1.0f / 1048576.0f)   // 1 / (4*512*512) pixels per channel
#define NPART     256             // hist blocks -> number of partial histograms

// ---------------- Kernel 1: per-block sub-bin histogram, plain stores ------
__global__ __launch_bounds__(1024) void hist_kernel(const float* __restrict__ in,
                                                    unsigned* __restrict__ partial) {
    __shared__ unsigned lhist[NHIST];
    for (int i = threadIdx.x; i < NHIST; i += blockDim.x) lhist[i] = 0u;
    __syncthreads();

    const int stride = gridDim.x * blockDim.x;
    for (int idx = blockIdx.x * blockDim.x + threadIdx.x; idx < NVEC; idx += stride) {
        const int u = idx * 4;                 // compact float index over 3-channel data
        const int b = u / PER_BATCH;           // batch (magic-mul)
        const int r = u - b * PER_BATCH;       // offset within batch's 3-channel block
        const int ch = r >> 18;                // / HW -> channel 0..2 (same for all 4 lanes-of-4)
        const float4 v = *reinterpret_cast<const float4*>(in + (size_t)b * (4 * HW) + r);
        const float vals[4] = {v.x, v.y, v.z, v.w};
#pragma unroll
        for (int j = 0; j < 4; ++j) {
            // q = round(127.5*(x+1)*KSUB) = round(1020*x + 1020)
            int q = __float2int_rn(fmaf(vals[j], 1020.0f, 1020.0f));
            q = min(max(q, 0), NSUB - 1);
            atomicAdd(&lhist[ch * NSUB + q], 1u);
        }
    }
    __syncthreads();

    unsigned* dst = partial + (size_t)blockIdx.x * NHIST;
    for (int i = threadIdx.x; i < NHIST; i += blockDim.x) dst[i] = lhist[i];
}

// ---------------- Kernel 2: column reduce over NPART partials --------------
__global__ __launch_bounds__(128) void reduce_kernel(const unsigned* __restrict__ partial,
                                                     float* __restrict__ fhist) {
    const int p = blockIdx.x * 128 + threadIdx.x;   // 0..NHIST-1, coalesced
    unsigned s0 = 0, s1 = 0, s2 = 0, s3 = 0;
#pragma unroll 4
    for (int r = 0; r < NPART; r += 4) {
        s0 += partial[(size_t)(r + 0) * NHIST + p];
        s1 += partial[(size_t)(r + 1) * NHIST + p];
        s2 += partial[(size_t)(r + 2) * NHIST + p];
        s3 += partial[(size_t)(r + 3) * NHIST + p];
    }
    fhist[p] = (float)(s0 + s1 + s2 + s3);
}

// ---------------- Kernel 3: Gaussian conv over sub-bins + L2 loss ----------
__global__ __launch_bounds__(256) void conv_loss_kernel(const float* __restrict__ fhist,
                                                        float* __restrict__ out) {
    __shared__ float fh[NHIST];
    __shared__ float w[2 * WIN + 1];
    __shared__ float red[256];

    for (int i = threadIdx.x; i < NHIST; i += 256) fh[i] = fhist[i];
    for (int i = threadIdx.x; i < 2 * WIN + 1; i += 256) {
        const float d = (float)(i - WIN) / (float)KSUB;
        w[i] = 0.5f * expf(-0.5f * d * d);
    }
    __syncthreads();

    float acc = 0.0f;
    for (int p = threadIdx.x; p < 768; p += 256) {          // 3 channels * 256 bins
        const int c = p >> 8;
        const int vbin = p & 255;
        const int center = vbin * KSUB;
        const int q0 = max(center - WIN, 0);
        const int q1 = min(center + WIN, NSUB - 1);
        float s = 0.0f;
        for (int q = q0; q <= q1; ++q)
            s += fh[c * NSUB + q] * w[q - center + WIN];
        const float h = s * P_INV;
        const float d = h - (1.0f / 256.0f);
        acc += d * d;
    }

    red[threadIdx.x] = acc;
    __syncthreads();
    for (int off = 128; off > 0; off >>= 1) {
        if (threadIdx.x < off) red[threadIdx.x] += red[threadIdx.x + off];
        __syncthreads();
    }
    if (threadIdx.x == 0) out[0] = red[0];
}

// ---------------------------------------------------------------------------
extern "C" void kernel_launch(void* const* d_in, const int* in_sizes, int n_in,
                              void* d_out, int out_size, void* d_ws, size_t ws_size,
                              hipStream_t stream) {
    const float* in = (const float*)d_in[0];
    float* out = (float*)d_out;
    unsigned* partial = (unsigned*)d_ws;                       // NPART*NHIST u32 = 6 MB
    float* fhist = (float*)((char*)d_ws + (size_t)NPART * NHIST * sizeof(unsigned));

    hist_kernel<<<NPART, 1024, 0, stream>>>(in, partial);
    reduce_kernel<<<NHIST / 128, 128, 0, stream>>>(partial, fhist);
    conv_loss_kernel<<<1, 256, 0, stream>>>(fhist, out);
}